// Round 4
// baseline (234.613 us; speedup 1.0000x reference)
//
#include <hip/hip_runtime.h>
#include <hip/hip_bf16.h>
#include <math.h>

// Shapes (fixed): B=2048, D=1024, H=1024, Z=256, E=64
// out = concat(h1[B,H], c1[B,H], hhat1[B,Z], chat1[B,Z]) fp32
//
// Pipeline (4 launches):
//  1. k_prep      : pack hcat bf16 + build combined Bt (hyper cols gate-interleaved)
//                   + small transposes
//  2. k_gemm_main : C[2048][5120] = hcat @ [pad|W ; hW-perm], natural dim3(40,16) grid
//                   (bx fastest -> per-XCD working set = 1 A-panel + 5 B-panels, fits L2);
//                   hyper blocks run the hyper LSTM cell in-epilogue (shfl gates)
//  3. k_gemm_z    : z = hhat1 @ [zw_h|zw_x|zw_b] + bias   (bf16 out)
//  4. k_dmod_lstm : block-diag d-einsum + modulation + main LSTM cell
//                   (grawb tile staged via GLL16, dbuf)

typedef __attribute__((ext_vector_type(8))) short bf16x8;
typedef __attribute__((ext_vector_type(4))) float f32x4;
typedef unsigned short u16;

__device__ __forceinline__ u16 f2b(float f) {
  union { float f; unsigned u; } v; v.f = f;
  unsigned r = v.u + 0x7fffu + ((v.u >> 16) & 1u);   // RNE
  return (u16)(r >> 16);
}
__device__ __forceinline__ float b2f(u16 b) {
  union { unsigned u; float f; } v; v.u = ((unsigned)b) << 16; return v.f;
}
__device__ __forceinline__ float sigm(float x) { return 1.f / (1.f + __expf(-x)); }

#define GLL16(gsrc, ldst)                                                      \
  __builtin_amdgcn_global_load_lds(                                            \
      (const __attribute__((address_space(1))) void*)(gsrc),                   \
      (__attribute__((address_space(3))) void*)(ldst), 16, 0, 0)

// ---------------- merged prep ----------------
// blocks [0,4608)            : pack hcat = [hhat0|h0|x] -> bf16 [2048][2304]
// blocks [4608, 4608+5760)   : build Bt [5120][2304] (skip n<4096,k<256 pad)
//                              hyper rows permuted: bt row 4096+z*4+g <- hW col g*256+z
// blocks [10368, 10368+480)  : zwT (3x 256x256) + dwT (12x 64x1024 -> 1024x64)
__global__ void k_prep(const float* __restrict__ hhat0, const float* __restrict__ h0,
                       const float* __restrict__ x, const float* __restrict__ weight,
                       const float* __restrict__ hweight,
                       const float* __restrict__ zw_h, const float* __restrict__ zw_x,
                       const float* __restrict__ zw_b, const float* __restrict__ dw_h,
                       const float* __restrict__ dw_x, const float* __restrict__ dw_b,
                       u16* __restrict__ hcatb, u16* __restrict__ bt,
                       u16* __restrict__ zwT, u16* __restrict__ dwT) {
  __shared__ float tile[32][66];
  int bid = blockIdx.x;
  const int t = threadIdx.x;
  if (bid < 4608) {
    int i = bid * 256 + t;                 // over 2048*576 float4s
    int b = i / 576, c4 = i % 576;
    const float* src;
    if (c4 < 64)       src = hhat0 + (long)b * 256 + c4 * 4;
    else if (c4 < 320) src = h0 + (long)b * 1024 + (c4 - 64) * 4;
    else               src = x + (long)b * 1024 + (c4 - 320) * 4;
    float4 v = *(const float4*)src;
    ushort4 o = {f2b(v.x), f2b(v.y), f2b(v.z), f2b(v.w)};
    *(ushort4*)&hcatb[(long)b * 2304 + c4 * 4] = o;
    return;
  }
  bid -= 4608;
  if (bid < 5760) {                        // build Bt
    const int n0 = (bid % 160) * 32, k0 = (bid / 160) * 64;
    if (n0 < 4096 && k0 < 256) return;
    const int isH = (n0 >= 4096);
    const float* src; int C, sc0, sr0;
    if (isH) { src = hweight; C = 1024; sc0 = n0 - 4096; sr0 = k0; }
    else     { src = weight;  C = 4096; sc0 = n0;        sr0 = k0 - 256; }
    #pragma unroll
    for (int p = 0; p < 8; ++p) {
      int c = t & 31, r = (t >> 5) + 8 * p;
      tile[c][r] = src[(long)(sr0 + r) * C + sc0 + c];
    }
    __syncthreads();
    #pragma unroll
    for (int p = 0; p < 2; ++p) {
      int kc = t & 15, cl = (t >> 4) + 16 * p;
      int orow;
      if (isH) { int u = sc0 + cl; orow = 4096 + ((u & 255) << 2) + (u >> 8); }
      else     orow = n0 + cl;
      ushort4 o = {f2b(tile[cl][4 * kc]), f2b(tile[cl][4 * kc + 1]),
                   f2b(tile[cl][4 * kc + 2]), f2b(tile[cl][4 * kc + 3])};
      *(ushort4*)&bt[(long)orow * 2304 + k0 + 4 * kc] = o;
    }
    return;
  }
  bid -= 5760;                             // small transposes
  const int zi = bid >> 5, bx = bid & 31;
  const float* src; u16* dst; int R, C;
  if (zi < 3) {
    src = (zi == 0) ? zw_h : (zi == 1) ? zw_x : zw_b;
    dst = zwT + (long)zi * 65536; R = 256; C = 256;
  } else {
    int s = zi - 3, tt = s >> 2, g = s & 3;
    src = ((tt == 0) ? dw_h : (tt == 1) ? dw_x : dw_b) + (long)g * 65536;
    dst = dwT + (long)s * 65536; R = 64; C = 1024;
  }
  const int nct = C / 32;
  const int c0 = (bx % nct) * 32, r0 = (bx / nct) * 64;
  #pragma unroll
  for (int p = 0; p < 8; ++p) {
    int c = t & 31, r = (t >> 5) + 8 * p;
    tile[c][r] = src[(long)(r0 + r) * C + c0 + c];
  }
  __syncthreads();
  #pragma unroll
  for (int p = 0; p < 2; ++p) {
    int kc = t & 15, cl = (t >> 4) + 16 * p;
    ushort4 o = {f2b(tile[cl][4 * kc]), f2b(tile[cl][4 * kc + 1]),
                 f2b(tile[cl][4 * kc + 2]), f2b(tile[cl][4 * kc + 3])};
    *(ushort4*)&dst[(long)(c0 + cl) * R + r0 + 4 * kc] = o;
  }
}

// ---------------- main GEMM: 512 threads, 128x128 tile, BK=64 single-buffer ----------------
// A [2048][2304] bf16, Bt [5120][2304] bf16.  n<4096 -> kstart=256, bf16 out (grawb);
// n>=4096 -> full K, hyper LSTM cell computed in-epilogue (gate-interleaved cols).
// 32KB LDS; natural dim3(40,16) grid: bx varies fastest, so in-flight blocks share
// one by (A-panel) -> per-XCD L2 working set ~3.5MB (1 A-panel + ~5 B-panels), fits.
__global__ __launch_bounds__(512, 4)
void k_gemm_main(const u16* __restrict__ A, const u16* __restrict__ Bt,
                 const float* __restrict__ hbias, const float* __restrict__ chat0,
                 u16* __restrict__ grawb, float* __restrict__ chat1,
                 float* __restrict__ hhat1, u16* __restrict__ hhat1b) {
  constexpr int K = 2304, BK = 64;
  __shared__ __align__(16) u16 sA[128 * BK];   // 16KB
  __shared__ __align__(16) u16 sB[128 * BK];   // 16KB
  const int m0 = blockIdx.y * 128, n0 = blockIdx.x * 128;
  const int kstart = (n0 < 4096) ? 256 : 0;
  const int tid = threadIdx.x, wave = tid >> 6, lane = tid & 63;
  const int quad = lane >> 4, lrow = lane & 15;
  const int wm = (wave >> 2) * 64, wn = (wave & 3) * 32;

  // staging addressing: two 8KB halves per operand per K-step.
  const int la = tid * 16;
  const int rowa = la >> 7, qa = (((la >> 4) & 7) - rowa) & 7;
  const int lb = 8192 + tid * 16;
  const int rowb = lb >> 7, qb = (((lb >> 4) & 7) - rowb) & 7;
  const long aoff0 = ((long)(m0 + rowa) * K + qa * 8) * 2;
  const long aoff1 = ((long)(m0 + rowb) * K + qb * 8) * 2;
  const long boff0 = ((long)(n0 + rowa) * K + qa * 8) * 2;
  const long boff1 = ((long)(n0 + rowb) * K + qb * 8) * 2;

  const f32x4 vz = {0.f, 0.f, 0.f, 0.f};
  f32x4 acc[4][2];
  #pragma unroll
  for (int i = 0; i < 4; ++i)
    #pragma unroll
    for (int j = 0; j < 2; ++j) acc[i][j] = vz;

  for (int k0 = kstart; k0 < K; k0 += BK) {
    GLL16((const char*)A + aoff0 + (long)k0 * 2, (char*)sA + wave * 1024);
    GLL16((const char*)A + aoff1 + (long)k0 * 2, (char*)sA + 8192 + wave * 1024);
    GLL16((const char*)Bt + boff0 + (long)k0 * 2, (char*)sB + wave * 1024);
    GLL16((const char*)Bt + boff1 + (long)k0 * 2, (char*)sB + 8192 + wave * 1024);
    __syncthreads();

    bf16x8 af[4][2], bf[2][2];
    #pragma unroll
    for (int i = 0; i < 4; ++i) {
      int row = wm + i * 16 + lrow;
      const char* base = (const char*)sA + row * 128;
      af[i][0] = *(const bf16x8*)(base + (((quad + row) & 7) << 4));
      af[i][1] = *(const bf16x8*)(base + (((4 + quad + row) & 7) << 4));
    }
    #pragma unroll
    for (int j = 0; j < 2; ++j) {
      int row = wn + j * 16 + lrow;
      const char* base = (const char*)sB + row * 128;
      bf[j][0] = *(const bf16x8*)(base + (((quad + row) & 7) << 4));
      bf[j][1] = *(const bf16x8*)(base + (((4 + quad + row) & 7) << 4));
    }
    #pragma unroll
    for (int kk = 0; kk < 2; ++kk)
      #pragma unroll
      for (int i = 0; i < 4; ++i)
        #pragma unroll
        for (int j = 0; j < 2; ++j)
          acc[i][j] = __builtin_amdgcn_mfma_f32_16x16x32_bf16(af[i][kk], bf[j][kk], acc[i][j], 0, 0, 0);
    __syncthreads();
  }

  if (n0 < 4096) {
    #pragma unroll
    for (int i = 0; i < 4; ++i)
      #pragma unroll
      for (int j = 0; j < 2; ++j)
        #pragma unroll
        for (int r = 0; r < 4; ++r) {
          int row = m0 + wm + i * 16 + quad * 4 + r;
          int col = n0 + wn + j * 16 + lrow;
          grawb[(long)row * 4096 + col] = f2b(acc[i][j][r]);
        }
  } else {
    // hyper cell: col u = z*4+g; 4 gates of one z live in 4 consecutive lanes.
    const int ubase = (n0 - 4096) + wn;
    #pragma unroll
    for (int i = 0; i < 4; ++i) {
      #pragma unroll
      for (int j = 0; j < 2; ++j) {
        int u = ubase + j * 16 + lrow;
        int g = u & 3, z = u >> 2;
        #pragma unroll
        for (int r = 0; r < 4; ++r) {
          int row = m0 + wm + i * 16 + quad * 4 + r;
          float v = acc[i][j][r] + hbias[g * 256 + z];
          float vi = __shfl(v, (lane & ~3) + 0);
          float vg = __shfl(v, (lane & ~3) + 1);
          float vf = __shfl(v, (lane & ~3) + 2);
          float vo = __shfl(v, (lane & ~3) + 3);
          float cc = sigm(vf) * chat0[(long)row * 256 + z] + sigm(vi) * tanhf(vg);
          float hh = sigm(vo) * tanhf(cc);
          if (g == 0) {
            chat1[(long)row * 256 + z] = cc;
            hhat1[(long)row * 256 + z] = hh;
            hhat1b[(long)row * 256 + z] = f2b(hh);
          }
        }
      }
    }
  }
}

// ---------------- z GEMM: 256 threads, 64x128 tile ----------------
// A = hhat1b [2048][256], Bt = zwT [768][256]. out bf16 zb16 [2048][768] + zbias.
__global__ __launch_bounds__(256, 2)
void k_gemm_z(const u16* __restrict__ A, const u16* __restrict__ Bt,
              const float* __restrict__ zbh, const float* __restrict__ zbx,
              u16* __restrict__ zbout) {
  constexpr int K = 256, BK = 32;
  __shared__ __align__(16) u16 sA[64 * BK];
  __shared__ __align__(16) u16 sB[128 * BK];
  const int m0 = blockIdx.y * 64, n0 = blockIdx.x * 128;
  const int tid = threadIdx.x, wave = tid >> 6, lane = tid & 63;
  const int quad = lane >> 4, lrow = lane & 15;
  const int wm = (wave >> 1) * 32, wn = (wave & 1) * 64;

  const int sl = tid * 16;
  const int arow = sl >> 6;
  const int aq = (((sl & 63) >> 4) - (arow >> 1)) & 3;
  const long aoff = ((long)(m0 + arow) * K) * 2 + aq * 16;

  const f32x4 vz = {0.f, 0.f, 0.f, 0.f};
  f32x4 acc[2][4];
  #pragma unroll
  for (int i = 0; i < 2; ++i)
    #pragma unroll
    for (int j = 0; j < 4; ++j) acc[i][j] = vz;

  for (int k0 = 0; k0 < K; k0 += BK) {
    GLL16((const char*)A + aoff + (long)k0 * 2, (char*)sA + wave * 1024);
    #pragma unroll
    for (int c = 0; c < 2; ++c) {
      int l = c * 4096 + sl;
      int row = l >> 6;
      int q = (((l & 63) >> 4) - (row >> 1)) & 3;
      const char* g = (const char*)Bt + ((long)(n0 + row) * K + k0) * 2 + q * 16;
      GLL16(g, (char*)sB + c * 4096 + wave * 1024);
    }
    __syncthreads();
    bf16x8 af[2], bf[4];
    #pragma unroll
    for (int i = 0; i < 2; ++i) {
      int row = wm + i * 16 + lrow;
      af[i] = *(const bf16x8*)((const char*)sA + row * 64 + (((quad + (row >> 1)) & 3) << 4));
    }
    #pragma unroll
    for (int j = 0; j < 4; ++j) {
      int row = wn + j * 16 + lrow;
      bf[j] = *(const bf16x8*)((const char*)sB + row * 64 + (((quad + (row >> 1)) & 3) << 4));
    }
    #pragma unroll
    for (int i = 0; i < 2; ++i)
      #pragma unroll
      for (int j = 0; j < 4; ++j)
        acc[i][j] = __builtin_amdgcn_mfma_f32_16x16x32_bf16(af[i], bf[j], acc[i][j], 0, 0, 0);
    __syncthreads();
  }
  #pragma unroll
  for (int i = 0; i < 2; ++i) {
    #pragma unroll
    for (int j = 0; j < 4; ++j) {
      #pragma unroll
      for (int r = 0; r < 4; ++r) {
        int row = m0 + wm + i * 16 + quad * 4 + r;
        int col = n0 + wn + j * 16 + lrow;
        float v = acc[i][j][r] + ((col < 256) ? zbh[col] : (col < 512) ? zbx[col - 256] : 0.f);
        zbout[(long)row * 768 + col] = f2b(v);
      }
    }
  }
}

// ---------------- fused d-einsum + modulation + main cell ----------------
// Per gate: staging loads z strips, 3 dwT slices AND the grawb tile (GLL16, dbuf);
// then 3 MFMA chains (aH/aX/aB); epilogue reads grawb from LDS (no scalar global).
__global__ __launch_bounds__(256, 2)
void k_dmod_lstm(const u16* __restrict__ z, const u16* __restrict__ dwT,
                 const u16* __restrict__ grawb, const float* __restrict__ bias,
                 const float* __restrict__ c0, float* __restrict__ h1,
                 float* __restrict__ c1) {
  __shared__ __align__(16) u16 sZ[64 * 192];     // 24576 B
  __shared__ __align__(16) u16 sW[3 * 64 * 64];  // 24576 B
  __shared__ __align__(16) u16 sG[2][64 * 64];   // 2 x 8192 B (dbuf: epilogue(g) vs stage(g+1))
  const int m0 = blockIdx.y * 64;
  const int hc0 = blockIdx.x * 64;
  const int tid = threadIdx.x, wave = tid >> 6, lane = tid & 63;
  const int quad = lane >> 4, lrow = lane & 15;
  const int wm = (wave >> 1) * 32, wn = (wave & 1) * 32;
  const f32x4 vz4 = {0.f, 0.f, 0.f, 0.f};

  f32x4 pcar[2][2];   // progressive carry: sigm(i) -> sigm(i)*tanh(g)
  f32x4 ccar[2][2];   // c1

  #pragma unroll
  for (int g = 0; g < 4; ++g) {
    // ---- stage ----
    #pragma unroll
    for (int c = 0; c < 6; ++c) {
      int l = c * 4096 + tid * 16;
      // sZ: rows of 24 chunks
      int ci = l >> 4, row = ci / 24, p = ci - row * 24;
      int q = p + 72 - row; q -= (q / 24) * 24;            // (p - row) mod 24
      int tt = q >> 3, e16 = q & 7;
      const char* gz = (const char*)z + (long)(m0 + row) * 1536 + tt * 512 + g * 128 + e16 * 16;
      GLL16(gz, (char*)sZ + c * 4096 + wave * 1024);
      // sW: 3 slices of 64 rows x 8 chunks
      int t2 = l >> 13, rw = (l & 8191) >> 7, p2 = (l >> 4) & 7;
      int q2 = (p2 - rw) & 7;
      const char* gw = (const char*)dwT + (long)((t2 * 4 + g) * 1024 + hc0 + rw) * 128 + q2 * 16;
      GLL16(gw, (char*)sW + c * 4096 + wave * 1024);
    }
    // sG: 64 rows x 128B tile of grawb for this gate (linear, scalar-read later)
    #pragma unroll
    for (int c = 0; c < 2; ++c) {
      int l = c * 4096 + tid * 16;
      int row = l >> 7, off = l & 127;
      const char* gg = (const char*)grawb + ((long)(m0 + row) * 4096 + g * 1024 + hc0) * 2 + off;
      GLL16(gg, (char*)sG[g & 1] + c * 4096 + wave * 1024);
    }
    __syncthreads();
    // ---- MFMA ----
    f32x4 aH[2][2], aX[2][2], aB[2][2];
    #pragma unroll
    for (int i = 0; i < 2; ++i)
      #pragma unroll
      for (int j = 0; j < 2; ++j) { aH[i][j] = vz4; aX[i][j] = vz4; aB[i][j] = vz4; }
    #pragma unroll
    for (int kk = 0; kk < 2; ++kk) {
      bf16x8 za[3][2], wb[3][2];
      #pragma unroll
      for (int t = 0; t < 3; ++t) {
        #pragma unroll
        for (int i = 0; i < 2; ++i) {
          int row = wm + i * 16 + lrow;
          int q0 = t * 8 + kk * 4 + quad;
          int ph = q0 + row; ph -= (ph / 24) * 24;
          za[t][i] = *(const bf16x8*)((const char*)sZ + row * 384 + ph * 16);
        }
        #pragma unroll
        for (int j = 0; j < 2; ++j) {
          int row = wn + j * 16 + lrow;
          int q0 = kk * 4 + quad;
          int ph = (q0 + row) & 7;
          wb[t][j] = *(const bf16x8*)((const char*)sW + t * 8192 + row * 128 + ph * 16);
        }
      }
      #pragma unroll
      for (int i = 0; i < 2; ++i)
        #pragma unroll
        for (int j = 0; j < 2; ++j) {
          aH[i][j] = __builtin_amdgcn_mfma_f32_16x16x32_bf16(za[0][i], wb[0][j], aH[i][j], 0, 0, 0);
          aX[i][j] = __builtin_amdgcn_mfma_f32_16x16x32_bf16(za[1][i], wb[1][j], aX[i][j], 0, 0, 0);
          aB[i][j] = __builtin_amdgcn_mfma_f32_16x16x32_bf16(za[2][i], wb[2][j], aB[i][j], 0, 0, 0);
        }
    }
    __syncthreads();
    // ---- per-gate epilogue (grawb from LDS) ----
    const u16* sGc = sG[g & 1];
    #pragma unroll
    for (int i = 0; i < 2; ++i) {
      #pragma unroll
      for (int j = 0; j < 2; ++j) {
        #pragma unroll
        for (int r = 0; r < 4; ++r) {
          int rowl = wm + i * 16 + quad * 4 + r;
          int col = wn + j * 16 + lrow;
          int row = m0 + rowl;
          float gr = b2f(sGc[rowl * 64 + col]);
          float v = gr * aH[i][j][r] * aX[i][j][r] + aB[i][j][r] + bias[g * 1024 + hc0 + col];
          long idx = (long)row * 1024 + hc0 + col;
          if (g == 0) pcar[i][j][r] = sigm(v);
          else if (g == 1) pcar[i][j][r] *= tanhf(v);
          else if (g == 2) {
            float cc = sigm(v) * c0[idx] + pcar[i][j][r];
            ccar[i][j][r] = cc;
            c1[idx] = cc;
          } else {
            h1[idx] = sigm(v) * tanhf(ccar[i][j][r]);
          }
        }
      }
    }
  }
}

// ---------------- launch ----------------

extern "C" void kernel_launch(void* const* d_in, const int* in_sizes, int n_in,
                              void* d_out, int out_size, void* d_ws, size_t ws_size,
                              hipStream_t stream) {
  const float* x      = (const float*)d_in[0];
  const float* h0     = (const float*)d_in[1];
  const float* c0     = (const float*)d_in[2];
  const float* hhat0  = (const float*)d_in[3];
  const float* chat0  = (const float*)d_in[4];
  const float* hweight= (const float*)d_in[5];
  const float* hbias  = (const float*)d_in[6];
  const float* zw_h   = (const float*)d_in[7];
  const float* zw_x   = (const float*)d_in[8];
  const float* zw_b   = (const float*)d_in[9];
  const float* zb_h   = (const float*)d_in[10];
  const float* zb_x   = (const float*)d_in[11];
  const float* dw_h   = (const float*)d_in[12];
  const float* dw_x   = (const float*)d_in[13];
  const float* dw_b   = (const float*)d_in[14];
  const float* weight = (const float*)d_in[15];
  const float* bias   = (const float*)d_in[16];
  float* out = (float*)d_out;

  char* w = (char*)d_ws;
  auto take = [&](size_t bytes) { char* p = w; w += (bytes + 255) & ~(size_t)255; return p; };
  u16*   hcatb  = (u16*)take(2048ull * 2304 * 2);
  u16*   btc    = (u16*)take(5120ull * 2304 * 2);
  u16*   zwT    = (u16*)take(768ull * 256 * 2);
  u16*   dwT    = (u16*)take(12ull * 1024 * 64 * 2);
  u16*   grawb  = (u16*)take(2048ull * 4096 * 2);
  u16*   hhat1b = (u16*)take(2048ull * 256 * 2);
  u16*   zb16   = (u16*)take(2048ull * 768 * 2);

  float* h1_o    = out;
  float* c1_o    = out + 2048 * 1024;
  float* hhat1_o = out + 2 * 2048 * 1024;
  float* chat1_o = out + 2 * 2048 * 1024 + 2048 * 256;

  k_prep<<<4608 + 5760 + 480, 256, 0, stream>>>(
      hhat0, h0, x, weight, hweight, zw_h, zw_x, zw_b, dw_h, dw_x, dw_b,
      hcatb, btc, zwT, dwT);

  k_gemm_main<<<dim3(40, 16), 512, 0, stream>>>(hcatb, btc, hbias, chat0,
                                                grawb, chat1_o, hhat1_o, hhat1b);

  k_gemm_z<<<dim3(6, 32), 256, 0, stream>>>(hhat1b, zwT, zb_h, zb_x, zb16);

  k_dmod_lstm<<<dim3(16, 32), 256, 0, stream>>>(zb16, dwT, grawb, bias, c0, h1_o, c1_o);
}

// Round 5
// 216.034 us; speedup vs baseline: 1.0860x; 1.0860x over previous
//
#include <hip/hip_runtime.h>
#include <hip/hip_bf16.h>
#include <math.h>

// Shapes (fixed): B=2048, D=1024, H=1024, Z=256, E=64
// out = concat(h1[B,H], c1[B,H], hhat1[B,Z], chat1[B,Z]) fp32
//
// Pipeline (4 launches):
//  1. k_prep      : pack hcat bf16 + build combined Bt (hyper cols gate-interleaved)
//  2. k_gemm_main : C[2048][5120] = hcat @ [pad|W ; hW-perm], natural dim3(40,16) grid;
//                   hyper blocks run the hyper LSTM cell in-epilogue,
//                   DEDUPED via quad 4x4 shfl_xor transpose (1 cell/lane, fast tanh)
//  3. k_gemm_z    : z = hhat1 @ [zw_h|zw_x|zw_b] + bias   (bf16 out)
//  4. k_dmod_lstm : block-diag d-einsum + modulation + main LSTM cell

typedef __attribute__((ext_vector_type(8))) short bf16x8;
typedef __attribute__((ext_vector_type(4))) float f32x4;
typedef unsigned short u16;

__device__ __forceinline__ u16 f2b(float f) {
  union { float f; unsigned u; } v; v.f = f;
  unsigned r = v.u + 0x7fffu + ((v.u >> 16) & 1u);   // RNE
  return (u16)(r >> 16);
}
__device__ __forceinline__ float b2f(u16 b) {
  union { unsigned u; float f; } v; v.u = ((unsigned)b) << 16; return v.f;
}
__device__ __forceinline__ float sigm(float x) {
  return __builtin_amdgcn_rcpf(1.f + __expf(-x));
}
__device__ __forceinline__ float ftanh(float x) {
  float xc = fminf(fmaxf(x, -15.f), 15.f);
  float t = __expf(2.f * xc);
  return (t - 1.f) * __builtin_amdgcn_rcpf(t + 1.f);
}
__device__ __forceinline__ float sel4(float a, float b, float c, float d, int k) {
  return (k & 2) ? ((k & 1) ? d : c) : ((k & 1) ? b : a);
}

#define GLL16(gsrc, ldst)                                                      \
  __builtin_amdgcn_global_load_lds(                                            \
      (const __attribute__((address_space(1))) void*)(gsrc),                   \
      (__attribute__((address_space(3))) void*)(ldst), 16, 0, 0)

// ---------------- merged prep ----------------
// blocks [0,4608)            : pack hcat = [hhat0|h0|x] -> bf16 [2048][2304]
// blocks [4608, 4608+5760)   : build Bt [5120][2304] (skip n<4096,k<256 pad)
//                              hyper rows permuted: bt row 4096+z*4+g <- hW col g*256+z
// blocks [10368, 10368+480)  : zwT (3x 256x256) + dwT (12x 64x1024 -> 1024x64)
__global__ void k_prep(const float* __restrict__ hhat0, const float* __restrict__ h0,
                       const float* __restrict__ x, const float* __restrict__ weight,
                       const float* __restrict__ hweight,
                       const float* __restrict__ zw_h, const float* __restrict__ zw_x,
                       const float* __restrict__ zw_b, const float* __restrict__ dw_h,
                       const float* __restrict__ dw_x, const float* __restrict__ dw_b,
                       u16* __restrict__ hcatb, u16* __restrict__ bt,
                       u16* __restrict__ zwT, u16* __restrict__ dwT) {
  __shared__ float tile[32][66];
  int bid = blockIdx.x;
  const int t = threadIdx.x;
  if (bid < 4608) {
    int i = bid * 256 + t;                 // over 2048*576 float4s
    int b = i / 576, c4 = i % 576;
    const float* src;
    if (c4 < 64)       src = hhat0 + (long)b * 256 + c4 * 4;
    else if (c4 < 320) src = h0 + (long)b * 1024 + (c4 - 64) * 4;
    else               src = x + (long)b * 1024 + (c4 - 320) * 4;
    float4 v = *(const float4*)src;
    ushort4 o = {f2b(v.x), f2b(v.y), f2b(v.z), f2b(v.w)};
    *(ushort4*)&hcatb[(long)b * 2304 + c4 * 4] = o;
    return;
  }
  bid -= 4608;
  if (bid < 5760) {                        // build Bt
    const int n0 = (bid % 160) * 32, k0 = (bid / 160) * 64;
    if (n0 < 4096 && k0 < 256) return;
    const int isH = (n0 >= 4096);
    const float* src; int C, sc0, sr0;
    if (isH) { src = hweight; C = 1024; sc0 = n0 - 4096; sr0 = k0; }
    else     { src = weight;  C = 4096; sc0 = n0;        sr0 = k0 - 256; }
    #pragma unroll
    for (int p = 0; p < 8; ++p) {
      int c = t & 31, r = (t >> 5) + 8 * p;
      tile[c][r] = src[(long)(sr0 + r) * C + sc0 + c];
    }
    __syncthreads();
    #pragma unroll
    for (int p = 0; p < 2; ++p) {
      int kc = t & 15, cl = (t >> 4) + 16 * p;
      int orow;
      if (isH) { int u = sc0 + cl; orow = 4096 + ((u & 255) << 2) + (u >> 8); }
      else     orow = n0 + cl;
      ushort4 o = {f2b(tile[cl][4 * kc]), f2b(tile[cl][4 * kc + 1]),
                   f2b(tile[cl][4 * kc + 2]), f2b(tile[cl][4 * kc + 3])};
      *(ushort4*)&bt[(long)orow * 2304 + k0 + 4 * kc] = o;
    }
    return;
  }
  bid -= 5760;                             // small transposes
  const int zi = bid >> 5, bx = bid & 31;
  const float* src; u16* dst; int R, C;
  if (zi < 3) {
    src = (zi == 0) ? zw_h : (zi == 1) ? zw_x : zw_b;
    dst = zwT + (long)zi * 65536; R = 256; C = 256;
  } else {
    int s = zi - 3, tt = s >> 2, g = s & 3;
    src = ((tt == 0) ? dw_h : (tt == 1) ? dw_x : dw_b) + (long)g * 65536;
    dst = dwT + (long)s * 65536; R = 64; C = 1024;
  }
  const int nct = C / 32;
  const int c0 = (bx % nct) * 32, r0 = (bx / nct) * 64;
  #pragma unroll
  for (int p = 0; p < 8; ++p) {
    int c = t & 31, r = (t >> 5) + 8 * p;
    tile[c][r] = src[(long)(r0 + r) * C + c0 + c];
  }
  __syncthreads();
  #pragma unroll
  for (int p = 0; p < 2; ++p) {
    int kc = t & 15, cl = (t >> 4) + 16 * p;
    ushort4 o = {f2b(tile[cl][4 * kc]), f2b(tile[cl][4 * kc + 1]),
                 f2b(tile[cl][4 * kc + 2]), f2b(tile[cl][4 * kc + 3])};
    *(ushort4*)&dst[(long)(c0 + cl) * R + r0 + 4 * kc] = o;
  }
}

// ---------------- main GEMM: 512 threads, 128x128 tile, BK=64 single-buffer ----------------
// A [2048][2304] bf16, Bt [5120][2304] bf16.  n<4096 -> kstart=256, bf16 out (grawb);
// n>=4096 -> full K, hyper LSTM cell in-epilogue (deduped, 1 cell per lane).
__global__ __launch_bounds__(512, 4)
void k_gemm_main(const u16* __restrict__ A, const u16* __restrict__ Bt,
                 const float* __restrict__ hbias, const float* __restrict__ chat0,
                 u16* __restrict__ grawb, float* __restrict__ chat1,
                 float* __restrict__ hhat1, u16* __restrict__ hhat1b) {
  constexpr int K = 2304, BK = 64;
  __shared__ __align__(16) u16 sA[128 * BK];   // 16KB
  __shared__ __align__(16) u16 sB[128 * BK];   // 16KB
  const int m0 = blockIdx.y * 128, n0 = blockIdx.x * 128;
  const int kstart = (n0 < 4096) ? 256 : 0;
  const int tid = threadIdx.x, wave = tid >> 6, lane = tid & 63;
  const int quad = lane >> 4, lrow = lane & 15;
  const int wm = (wave >> 2) * 64, wn = (wave & 3) * 32;

  // staging addressing: two 8KB halves per operand per K-step.
  const int la = tid * 16;
  const int rowa = la >> 7, qa = (((la >> 4) & 7) - rowa) & 7;
  const int lb = 8192 + tid * 16;
  const int rowb = lb >> 7, qb = (((lb >> 4) & 7) - rowb) & 7;
  const long aoff0 = ((long)(m0 + rowa) * K + qa * 8) * 2;
  const long aoff1 = ((long)(m0 + rowb) * K + qb * 8) * 2;
  const long boff0 = ((long)(n0 + rowa) * K + qa * 8) * 2;
  const long boff1 = ((long)(n0 + rowb) * K + qb * 8) * 2;

  const f32x4 vz = {0.f, 0.f, 0.f, 0.f};
  f32x4 acc[4][2];
  #pragma unroll
  for (int i = 0; i < 4; ++i)
    #pragma unroll
    for (int j = 0; j < 2; ++j) acc[i][j] = vz;

  for (int k0 = kstart; k0 < K; k0 += BK) {
    GLL16((const char*)A + aoff0 + (long)k0 * 2, (char*)sA + wave * 1024);
    GLL16((const char*)A + aoff1 + (long)k0 * 2, (char*)sA + 8192 + wave * 1024);
    GLL16((const char*)Bt + boff0 + (long)k0 * 2, (char*)sB + wave * 1024);
    GLL16((const char*)Bt + boff1 + (long)k0 * 2, (char*)sB + 8192 + wave * 1024);
    __syncthreads();

    bf16x8 af[4][2], bf[2][2];
    #pragma unroll
    for (int i = 0; i < 4; ++i) {
      int row = wm + i * 16 + lrow;
      const char* base = (const char*)sA + row * 128;
      af[i][0] = *(const bf16x8*)(base + (((quad + row) & 7) << 4));
      af[i][1] = *(const bf16x8*)(base + (((4 + quad + row) & 7) << 4));
    }
    #pragma unroll
    for (int j = 0; j < 2; ++j) {
      int row = wn + j * 16 + lrow;
      const char* base = (const char*)sB + row * 128;
      bf[j][0] = *(const bf16x8*)(base + (((quad + row) & 7) << 4));
      bf[j][1] = *(const bf16x8*)(base + (((4 + quad + row) & 7) << 4));
    }
    #pragma unroll
    for (int kk = 0; kk < 2; ++kk)
      #pragma unroll
      for (int i = 0; i < 4; ++i)
        #pragma unroll
        for (int j = 0; j < 2; ++j)
          acc[i][j] = __builtin_amdgcn_mfma_f32_16x16x32_bf16(af[i][kk], bf[j][kk], acc[i][j], 0, 0, 0);
    __syncthreads();
  }

  if (n0 < 4096) {
    #pragma unroll
    for (int i = 0; i < 4; ++i)
      #pragma unroll
      for (int j = 0; j < 2; ++j)
        #pragma unroll
        for (int r = 0; r < 4; ++r) {
          int row = m0 + wm + i * 16 + quad * 4 + r;
          int col = n0 + wn + j * 16 + lrow;
          grawb[(long)row * 4096 + col] = f2b(acc[i][j][r]);
        }
  } else {
    // hyper cell, deduped: col u = z*4+g; quad (4 consecutive lanes) holds one z's
    // 4 gates (lane&3) x 4 row-regs (r). 3x shfl_xor transposes so lane q3 gets all
    // 4 gates for r=q3 and computes exactly ONE cell.
    const int ubase = (n0 - 4096) + wn;
    const int q3 = lane & 3;
    #pragma unroll
    for (int i = 0; i < 4; ++i) {
      #pragma unroll
      for (int j = 0; j < 2; ++j) {
        int u = ubase + j * 16 + lrow;
        int g = u & 3, z = u >> 2;          // g == q3
        float hb = hbias[g * 256 + z];
        float v0 = acc[i][j][0] + hb, v1 = acc[i][j][1] + hb;
        float v2 = acc[i][j][2] + hb, v3 = acc[i][j][3] + hb;
        // s0 = gate q3 (own), sd = gate q3^d (from partner), all for r = q3
        float s0 = sel4(v0, v1, v2, v3, q3);
        float s1 = __shfl_xor(sel4(v0, v1, v2, v3, q3 ^ 1), 1);
        float s2 = __shfl_xor(sel4(v0, v1, v2, v3, q3 ^ 2), 2);
        float s3 = __shfl_xor(sel4(v0, v1, v2, v3, q3 ^ 3), 3);
        // gate k = s_{q3^k}
        float vi = sel4(s0, s1, s2, s3, q3);
        float vg = sel4(s0, s1, s2, s3, q3 ^ 1);
        float vf = sel4(s0, s1, s2, s3, q3 ^ 2);
        float vo = sel4(s0, s1, s2, s3, q3 ^ 3);
        int row = m0 + wm + i * 16 + quad * 4 + q3;
        float cc = sigm(vf) * chat0[(long)row * 256 + z] + sigm(vi) * ftanh(vg);
        float hh = sigm(vo) * ftanh(cc);
        chat1[(long)row * 256 + z] = cc;
        hhat1[(long)row * 256 + z] = hh;
        hhat1b[(long)row * 256 + z] = f2b(hh);
      }
    }
  }
}

// ---------------- z GEMM: 256 threads, 64x128 tile ----------------
// A = hhat1b [2048][256], Bt = zwT [768][256]. out bf16 zb16 [2048][768] + zbias.
__global__ __launch_bounds__(256, 2)
void k_gemm_z(const u16* __restrict__ A, const u16* __restrict__ Bt,
              const float* __restrict__ zbh, const float* __restrict__ zbx,
              u16* __restrict__ zbout) {
  constexpr int K = 256, BK = 32;
  __shared__ __align__(16) u16 sA[64 * BK];
  __shared__ __align__(16) u16 sB[128 * BK];
  const int m0 = blockIdx.y * 64, n0 = blockIdx.x * 128;
  const int tid = threadIdx.x, wave = tid >> 6, lane = tid & 63;
  const int quad = lane >> 4, lrow = lane & 15;
  const int wm = (wave >> 1) * 32, wn = (wave & 1) * 64;

  const int sl = tid * 16;
  const int arow = sl >> 6;
  const int aq = (((sl & 63) >> 4) - (arow >> 1)) & 3;
  const long aoff = ((long)(m0 + arow) * K) * 2 + aq * 16;

  const f32x4 vz = {0.f, 0.f, 0.f, 0.f};
  f32x4 acc[2][4];
  #pragma unroll
  for (int i = 0; i < 2; ++i)
    #pragma unroll
    for (int j = 0; j < 4; ++j) acc[i][j] = vz;

  for (int k0 = 0; k0 < K; k0 += BK) {
    GLL16((const char*)A + aoff + (long)k0 * 2, (char*)sA + wave * 1024);
    #pragma unroll
    for (int c = 0; c < 2; ++c) {
      int l = c * 4096 + sl;
      int row = l >> 6;
      int q = (((l & 63) >> 4) - (row >> 1)) & 3;
      const char* g = (const char*)Bt + ((long)(n0 + row) * K + k0) * 2 + q * 16;
      GLL16(g, (char*)sB + c * 4096 + wave * 1024);
    }
    __syncthreads();
    bf16x8 af[2], bf[4];
    #pragma unroll
    for (int i = 0; i < 2; ++i) {
      int row = wm + i * 16 + lrow;
      af[i] = *(const bf16x8*)((const char*)sA + row * 64 + (((quad + (row >> 1)) & 3) << 4));
    }
    #pragma unroll
    for (int j = 0; j < 4; ++j) {
      int row = wn + j * 16 + lrow;
      bf[j] = *(const bf16x8*)((const char*)sB + row * 64 + (((quad + (row >> 1)) & 3) << 4));
    }
    #pragma unroll
    for (int i = 0; i < 2; ++i)
      #pragma unroll
      for (int j = 0; j < 4; ++j)
        acc[i][j] = __builtin_amdgcn_mfma_f32_16x16x32_bf16(af[i], bf[j], acc[i][j], 0, 0, 0);
    __syncthreads();
  }
  #pragma unroll
  for (int i = 0; i < 2; ++i) {
    #pragma unroll
    for (int j = 0; j < 4; ++j) {
      #pragma unroll
      for (int r = 0; r < 4; ++r) {
        int row = m0 + wm + i * 16 + quad * 4 + r;
        int col = n0 + wn + j * 16 + lrow;
        float v = acc[i][j][r] + ((col < 256) ? zbh[col] : (col < 512) ? zbx[col - 256] : 0.f);
        zbout[(long)row * 768 + col] = f2b(v);
      }
    }
  }
}

// ---------------- fused d-einsum + modulation + main cell ----------------
// Per gate: staging loads z strips, 3 dwT slices AND the grawb tile (GLL16, dbuf);
// then 3 MFMA chains (aH/aX/aB); epilogue reads grawb from LDS (no scalar global).
__global__ __launch_bounds__(256, 2)
void k_dmod_lstm(const u16* __restrict__ z, const u16* __restrict__ dwT,
                 const u16* __restrict__ grawb, const float* __restrict__ bias,
                 const float* __restrict__ c0, float* __restrict__ h1,
                 float* __restrict__ c1) {
  __shared__ __align__(16) u16 sZ[64 * 192];     // 24576 B
  __shared__ __align__(16) u16 sW[3 * 64 * 64];  // 24576 B
  __shared__ __align__(16) u16 sG[2][64 * 64];   // 2 x 8192 B (dbuf: epilogue(g) vs stage(g+1))
  const int m0 = blockIdx.y * 64;
  const int hc0 = blockIdx.x * 64;
  const int tid = threadIdx.x, wave = tid >> 6, lane = tid & 63;
  const int quad = lane >> 4, lrow = lane & 15;
  const int wm = (wave >> 1) * 32, wn = (wave & 1) * 32;
  const f32x4 vz4 = {0.f, 0.f, 0.f, 0.f};

  f32x4 pcar[2][2];   // progressive carry: sigm(i) -> sigm(i)*tanh(g)
  f32x4 ccar[2][2];   // c1

  #pragma unroll
  for (int g = 0; g < 4; ++g) {
    // ---- stage ----
    #pragma unroll
    for (int c = 0; c < 6; ++c) {
      int l = c * 4096 + tid * 16;
      // sZ: rows of 24 chunks
      int ci = l >> 4, row = ci / 24, p = ci - row * 24;
      int q = p + 72 - row; q -= (q / 24) * 24;            // (p - row) mod 24
      int tt = q >> 3, e16 = q & 7;
      const char* gz = (const char*)z + (long)(m0 + row) * 1536 + tt * 512 + g * 128 + e16 * 16;
      GLL16(gz, (char*)sZ + c * 4096 + wave * 1024);
      // sW: 3 slices of 64 rows x 8 chunks
      int t2 = l >> 13, rw = (l & 8191) >> 7, p2 = (l >> 4) & 7;
      int q2 = (p2 - rw) & 7;
      const char* gw = (const char*)dwT + (long)((t2 * 4 + g) * 1024 + hc0 + rw) * 128 + q2 * 16;
      GLL16(gw, (char*)sW + c * 4096 + wave * 1024);
    }
    // sG: 64 rows x 128B tile of grawb for this gate (linear, scalar-read later)
    #pragma unroll
    for (int c = 0; c < 2; ++c) {
      int l = c * 4096 + tid * 16;
      int row = l >> 7, off = l & 127;
      const char* gg = (const char*)grawb + ((long)(m0 + row) * 4096 + g * 1024 + hc0) * 2 + off;
      GLL16(gg, (char*)sG[g & 1] + c * 4096 + wave * 1024);
    }
    __syncthreads();
    // ---- MFMA ----
    f32x4 aH[2][2], aX[2][2], aB[2][2];
    #pragma unroll
    for (int i = 0; i < 2; ++i)
      #pragma unroll
      for (int j = 0; j < 2; ++j) { aH[i][j] = vz4; aX[i][j] = vz4; aB[i][j] = vz4; }
    #pragma unroll
    for (int kk = 0; kk < 2; ++kk) {
      bf16x8 za[3][2], wb[3][2];
      #pragma unroll
      for (int t = 0; t < 3; ++t) {
        #pragma unroll
        for (int i = 0; i < 2; ++i) {
          int row = wm + i * 16 + lrow;
          int q0 = t * 8 + kk * 4 + quad;
          int ph = q0 + row; ph -= (ph / 24) * 24;
          za[t][i] = *(const bf16x8*)((const char*)sZ + row * 384 + ph * 16);
        }
        #pragma unroll
        for (int j = 0; j < 2; ++j) {
          int row = wn + j * 16 + lrow;
          int q0 = kk * 4 + quad;
          int ph = (q0 + row) & 7;
          wb[t][j] = *(const bf16x8*)((const char*)sW + t * 8192 + row * 128 + ph * 16);
        }
      }
      #pragma unroll
      for (int i = 0; i < 2; ++i)
        #pragma unroll
        for (int j = 0; j < 2; ++j) {
          aH[i][j] = __builtin_amdgcn_mfma_f32_16x16x32_bf16(za[0][i], wb[0][j], aH[i][j], 0, 0, 0);
          aX[i][j] = __builtin_amdgcn_mfma_f32_16x16x32_bf16(za[1][i], wb[1][j], aX[i][j], 0, 0, 0);
          aB[i][j] = __builtin_amdgcn_mfma_f32_16x16x32_bf16(za[2][i], wb[2][j], aB[i][j], 0, 0, 0);
        }
    }
    __syncthreads();
    // ---- per-gate epilogue (grawb from LDS) ----
    const u16* sGc = sG[g & 1];
    #pragma unroll
    for (int i = 0; i < 2; ++i) {
      #pragma unroll
      for (int j = 0; j < 2; ++j) {
        #pragma unroll
        for (int r = 0; r < 4; ++r) {
          int rowl = wm + i * 16 + quad * 4 + r;
          int col = wn + j * 16 + lrow;
          int row = m0 + rowl;
          float gr = b2f(sGc[rowl * 64 + col]);
          float v = gr * aH[i][j][r] * aX[i][j][r] + aB[i][j][r] + bias[g * 1024 + hc0 + col];
          long idx = (long)row * 1024 + hc0 + col;
          if (g == 0) pcar[i][j][r] = sigm(v);
          else if (g == 1) pcar[i][j][r] *= ftanh(v);
          else if (g == 2) {
            float cc = sigm(v) * c0[idx] + pcar[i][j][r];
            ccar[i][j][r] = cc;
            c1[idx] = cc;
          } else {
            h1[idx] = sigm(v) * ftanh(ccar[i][j][r]);
          }
        }
      }
    }
  }
}

// ---------------- launch ----------------

extern "C" void kernel_launch(void* const* d_in, const int* in_sizes, int n_in,
                              void* d_out, int out_size, void* d_ws, size_t ws_size,
                              hipStream_t stream) {
  const float* x      = (const float*)d_in[0];
  const float* h0     = (const float*)d_in[1];
  const float* c0     = (const float*)d_in[2];
  const float* hhat0  = (const float*)d_in[3];
  const float* chat0  = (const float*)d_in[4];
  const float* hweight= (const float*)d_in[5];
  const float* hbias  = (const float*)d_in[6];
  const float* zw_h   = (const float*)d_in[7];
  const float* zw_x   = (const float*)d_in[8];
  const float* zw_b   = (const float*)d_in[9];
  const float* zb_h   = (const float*)d_in[10];
  const float* zb_x   = (const float*)d_in[11];
  const float* dw_h   = (const float*)d_in[12];
  const float* dw_x   = (const float*)d_in[13];
  const float* dw_b   = (const float*)d_in[14];
  const float* weight = (const float*)d_in[15];
  const float* bias   = (const float*)d_in[16];
  float* out = (float*)d_out;

  char* w = (char*)d_ws;
  auto take = [&](size_t bytes) { char* p = w; w += (bytes + 255) & ~(size_t)255; return p; };
  u16*   hcatb  = (u16*)take(2048ull * 2304 * 2);
  u16*   btc    = (u16*)take(5120ull * 2304 * 2);
  u16*   zwT    = (u16*)take(768ull * 256 * 2);
  u16*   dwT    = (u16*)take(12ull * 1024 * 64 * 2);
  u16*   grawb  = (u16*)take(2048ull * 4096 * 2);
  u16*   hhat1b = (u16*)take(2048ull * 256 * 2);
  u16*   zb16   = (u16*)take(2048ull * 768 * 2);

  float* h1_o    = out;
  float* c1_o    = out + 2048 * 1024;
  float* hhat1_o = out + 2 * 2048 * 1024;
  float* chat1_o = out + 2 * 2048 * 1024 + 2048 * 256;

  k_prep<<<4608 + 5760 + 480, 256, 0, stream>>>(
      hhat0, h0, x, weight, hweight, zw_h, zw_x, zw_b, dw_h, dw_x, dw_b,
      hcatb, btc, zwT, dwT);

  k_gemm_main<<<dim3(40, 16), 512, 0, stream>>>(hcatb, btc, hbias, chat0,
                                                grawb, chat1_o, hhat1_o, hhat1b);

  k_gemm_z<<<dim3(6, 32), 256, 0, stream>>>(hhat1b, zwT, zb_h, zb_x, zb16);

  k_dmod_lstm<<<dim3(16, 32), 256, 0, stream>>>(zb16, dwT, grawb, bias, c0, h1_o, c1_o);
}